// Round 1
// baseline (4794.001 us; speedup 1.0000x reference)
//
#include <hip/hip_runtime.h>
#include <hip/hip_bf16.h>
#include <math.h>

#define AUDIO_LEN 1310720
#define NBATCH    16
#define NFRAMES   2561
#define NFFT      2048
#define HALF_N    1024
#define NBINS_CQT 84
#define NBINS_SPEC 1025

// ws layout (float offsets)
#define WGT_OFF 0                       // 84*1025 = 86100 floats
#define TC_OFF  86112                   // 1025 floats (cos twiddle, k=0..1024)
#define TS_OFF  (TC_OFF + 1032)         // 1025 floats (sin twiddle)
#define WIN_OFF (TS_OFF + 1032)         // 2048 floats (Hann window)

__global__ __launch_bounds__(256) void init_tables_kernel(float* __restrict__ ws) {
    int i = blockIdx.x * 256 + threadIdx.x;
    if (i < NBINS_CQT * NBINS_SPEC) {
        int k = i / NBINS_SPEC;
        int f = i - k * NBINS_SPEC;
        float sf = (float)f * (22050.0f / 2048.0f);
        float cf = 27.5f * exp2f((float)k * (1.0f / 12.0f));
        ws[WGT_OFF + i] = expf(-fabsf(sf - cf) / (0.1f * cf));
    }
    if (i <= HALF_N) {
        double ang = -2.0 * M_PI * (double)i / 2048.0;
        ws[TC_OFF + i] = (float)cos(ang);
        ws[TS_OFF + i] = (float)sin(ang);
    }
    if (i < NFFT) {
        double ang = 2.0 * M_PI * (double)i / 2048.0;
        ws[WIN_OFF + i] = (float)(0.5 * (1.0 - cos(ang)));
    }
}

__global__ __launch_bounds__(256) void cqt_kernel(const float* __restrict__ audio,
                                                  const float* __restrict__ ws,
                                                  float* __restrict__ out) {
    __shared__ float SR[2][HALF_N];
    __shared__ float SI[2][HALF_N];
    __shared__ float Twr[HALF_N + 1];
    __shared__ float Twi[HALF_N + 1];
    __shared__ float mg[NBINS_SPEC];
    __shared__ float red[256];

    const int tid = threadIdx.x;
    const int ft  = blockIdx.x;
    const int b   = ft / NFRAMES;
    const int t   = ft - b * NFRAMES;

    const float* __restrict__ wgt = ws + WGT_OFF;
    const float* __restrict__ tc  = ws + TC_OFF;
    const float* __restrict__ tsn = ws + TS_OFF;
    const float* __restrict__ win = ws + WIN_OFF;

    // twiddle table -> LDS
    for (int i = tid; i <= HALF_N; i += 256) {
        Twr[i] = tc[i];
        Twi[i] = tsn[i];
    }

    // load frame with reflect padding, window, pack even/odd into complex
    const float* __restrict__ ab = audio + (size_t)b * AUDIO_LEN;
    const int base = t * 512 - 1024;
    for (int n = tid; n < NFFT; n += 256) {
        int j = base + n;
        if (j < 0) j = -j;
        else if (j >= AUDIO_LEN) j = 2 * AUDIO_LEN - 2 - j;
        float v = ab[j] * win[n];
        if (n & 1) SI[0][n >> 1] = v;
        else       SR[0][n >> 1] = v;
    }
    __syncthreads();

    // 10-stage radix-2 Stockham FFT (1024-point complex, natural order in/out)
    int cur = 0;
#pragma unroll
    for (int s = 0; s < 10; s++) {
        const int m = 1 << s;
#pragma unroll
        for (int ii = 0; ii < 2; ii++) {
            const int i = tid + ii * 256;           // butterfly index in [0,512)
            const int j = i >> s;                   // twiddle group
            const int tw = j << (s + 1);            // j * 2048/(2*half)
            const float wr = Twr[tw], wi = Twi[tw];
            const float c0r = SR[cur][i],       c0i = SI[cur][i];
            const float c1r = SR[cur][i + 512], c1i = SI[cur][i + 512];
            const float dr = c0r - c1r, di = c0i - c1i;
            const int o = i + (j << s);             // i + j*m
            SR[cur ^ 1][o]     = c0r + c1r;
            SI[cur ^ 1][o]     = c0i + c1i;
            SR[cur ^ 1][o + m] = wr * dr - wi * di;
            SI[cur ^ 1][o + m] = wr * di + wi * dr;
        }
        __syncthreads();
        cur ^= 1;
    }

    // untangle real-input FFT: X[k] = E[k] + W^k * O[k], k = 0..1024
    for (int k = tid; k <= HALF_N; k += 256) {
        const int k1 = k & (HALF_N - 1);
        const int k2 = (HALF_N - k) & (HALF_N - 1);
        const float zr = SR[cur][k1], zi = SI[cur][k1];
        const float ur = SR[cur][k2], ui = -SI[cur][k2];
        const float er = 0.5f * (zr + ur), ei = 0.5f * (zi + ui);
        const float dr = zr - ur,          di = zi - ui;
        const float pr = 0.5f * di,        pi = -0.5f * dr;
        const float wr = Twr[k],           wi = Twi[k];
        const float xr = er + wr * pr - wi * pi;
        const float xi = ei + wr * pi + wi * pr;
        mg[k] = sqrtf(xr * xr + xi * xi);
    }
    __syncthreads();

    // CQT projection: 3 threads per output bin
    const int kk   = tid / 3;
    const int part = tid - kk * 3;
    float acc = 0.0f;
    if (kk < NBINS_CQT) {
        const float* __restrict__ wrow = wgt + kk * NBINS_SPEC;
        for (int f = part; f < NBINS_SPEC; f += 3) acc += wrow[f] * mg[f];
    }
    red[tid] = acc;
    __syncthreads();
    if (kk < NBINS_CQT && part == 0) {
        const float sacc = red[tid] + red[tid + 1] + red[tid + 2];
        out[((size_t)b * NBINS_CQT + kk) * NFRAMES + t] = log10f(sacc + 1e-10f);
    }
}

extern "C" void kernel_launch(void* const* d_in, const int* in_sizes, int n_in,
                              void* d_out, int out_size, void* d_ws, size_t ws_size,
                              hipStream_t stream) {
    const float* audio = (const float*)d_in[0];
    float* out = (float*)d_out;
    float* ws  = (float*)d_ws;

    const int init_threads = NBINS_CQT * NBINS_SPEC;  // covers twiddle+window ranges too
    hipLaunchKernelGGL(init_tables_kernel,
                       dim3((init_threads + 255) / 256), dim3(256), 0, stream, ws);
    hipLaunchKernelGGL(cqt_kernel,
                       dim3(NBATCH * NFRAMES), dim3(256), 0, stream, audio, ws, out);
}

// Round 2
// 540.400 us; speedup vs baseline: 8.8712x; 8.8712x over previous
//
#include <hip/hip_runtime.h>
#include <hip/hip_bf16.h>
#include <math.h>

#define AUDIO_LEN 1310720
#define NBATCH    16
#define NFRAMES   2561
#define NT        (NBATCH * NFRAMES)   // 40976 frames total
#define NFFT      2048
#define HALF_N    1024
#define NK        84
#define NF        1025
#define WROW      1056                 // padded W row, floats (zero pad 1025..1055)
#define MROW      1032                 // padded mag row, bf16 shorts (zero pad 1025..1031)

// ws layout, float offsets
#define WGT_OFF  0                     // 84*1056 = 88704 floats
#define TW_OFF   (NK * WROW)           // float2[1025] -> 2050 floats (8B aligned)
#define WIN_OFF  (TW_OFF + 2052)       // 2048 floats
#define MAG_FOFF (WIN_OFF + 2048 + 4)  // = 92808 floats -> byte 371232 (16B aligned)

__device__ __forceinline__ float bf2f(unsigned short u) {
    union { unsigned u32; float f; } c;
    c.u32 = ((unsigned)u) << 16;
    return c.f;
}

__global__ __launch_bounds__(256) void init_tables_kernel(float* __restrict__ ws) {
    int i = blockIdx.x * 256 + threadIdx.x;
    if (i < NK * WROW) {
        int k = i / WROW;
        int f = i - k * WROW;
        float w = 0.0f;
        if (f < NF) {
            float sf = (float)f * (22050.0f / 2048.0f);
            float cf = 27.5f * exp2f((float)k * (1.0f / 12.0f));
            w = expf(-fabsf(sf - cf) / (0.1f * cf));
        }
        ws[WGT_OFF + i] = w;
    }
    if (i <= HALF_N) {
        double ang = -2.0 * M_PI * (double)i / 2048.0;
        ws[TW_OFF + 2 * i]     = (float)cos(ang);
        ws[TW_OFF + 2 * i + 1] = (float)sin(ang);
    }
    if (i < NFFT) {
        double ang = 2.0 * M_PI * (double)i / 2048.0;
        ws[WIN_OFF + i] = (float)(0.5 * (1.0 - cos(ang)));
    }
}

__global__ __launch_bounds__(256, 6) void fft_kernel(const float* __restrict__ audio,
                                                     const float* __restrict__ ws,
                                                     __hip_bfloat16* __restrict__ mag) {
    __shared__ float2 SC[2][HALF_N];
    __shared__ float2 TW[HALF_N + 1];

    const int tid = threadIdx.x;
    const int ft  = blockIdx.x;
    const int b   = ft / NFRAMES;
    const int t   = ft - b * NFRAMES;

    const float2* __restrict__ twg = (const float2*)(ws + TW_OFF);
    const float*  __restrict__ win = ws + WIN_OFF;

    for (int i = tid; i <= HALF_N; i += 256) TW[i] = twg[i];

    // load frame with reflect padding, window, pack even/odd into complex
    const float* __restrict__ ab = audio + (size_t)b * AUDIO_LEN;
    const int base = t * 512 - 1024;
    for (int n = tid; n < NFFT; n += 256) {
        int j = base + n;
        j = (j < 0) ? -j : ((j >= AUDIO_LEN) ? 2 * AUDIO_LEN - 2 - j : j);
        float v = ab[j] * win[n];
        if (n & 1) SC[0][n >> 1].y = v;
        else       SC[0][n >> 1].x = v;
    }
    __syncthreads();

    // 10-stage radix-2 Stockham FFT (1024-pt complex, natural order)
    int cur = 0;
#pragma unroll
    for (int s = 0; s < 10; s++) {
        const int m = 1 << s;
#pragma unroll
        for (int ii = 0; ii < 2; ii++) {
            const int i = tid + ii * 256;
            const int j = i >> s;
            const float2 w  = TW[j << (s + 1)];
            const float2 c0 = SC[cur][i];
            const float2 c1 = SC[cur][i + 512];
            const float dx = c0.x - c1.x, dy = c0.y - c1.y;
            const int o = i + (j << s);
            SC[cur ^ 1][o]     = make_float2(c0.x + c1.x, c0.y + c1.y);
            SC[cur ^ 1][o + m] = make_float2(w.x * dx - w.y * dy, w.x * dy + w.y * dx);
        }
        __syncthreads();
        cur ^= 1;
    }

    // untangle real-input FFT, magnitude, bf16 store
    __hip_bfloat16* __restrict__ mrow = mag + (size_t)ft * MROW;
    for (int k = tid; k <= HALF_N; k += 256) {
        const int k1 = k & (HALF_N - 1);
        const int k2 = (HALF_N - k) & (HALF_N - 1);
        const float2 z = SC[cur][k1];
        const float2 u = SC[cur][k2];
        const float er = 0.5f * (z.x + u.x), ei = 0.5f * (z.y - u.y);
        const float dr = z.x - u.x,          di = z.y + u.y;
        const float pr = 0.5f * di,          pi = -0.5f * dr;
        const float2 w = TW[k];
        const float xr = er + w.x * pr - w.y * pi;
        const float xi = ei + w.x * pi + w.y * pr;
        mrow[k] = __float2bfloat16(sqrtf(xr * xr + xi * xi));
    }
    if (tid < MROW - NF) mrow[NF + tid] = __float2bfloat16(0.0f);
}

// out[84, NT] = W[84, K] * mag[NT, K]^T, K-chunked GEMM, 64 frames x 84 bins per block
#define TFR 64
#define KF  32
#define NCH 33   // 33*32 = 1056 (pads are zero)

__global__ __launch_bounds__(256) void proj_kernel(const float* __restrict__ ws,
                                                   const __hip_bfloat16* __restrict__ mag,
                                                   float* __restrict__ out) {
    __shared__ float Wl[96][36];
    __shared__ float Ml[TFR][36];

    const int tid = threadIdx.x;
    const int ft0 = blockIdx.x * TFR;
    const int tx  = tid & 15;   // frame group
    const int ty  = tid >> 4;   // k group (16 groups x 6 k)

    float acc[6][4];
#pragma unroll
    for (int a = 0; a < 6; a++)
#pragma unroll
        for (int c = 0; c < 4; c++) acc[a][c] = 0.0f;

    const float* __restrict__ Wg = ws + WGT_OFF;

    for (int ch = 0; ch < NCH; ch++) {
        const int fk = ch * KF;
        // stage W chunk: 96 rows x 32 f (rows >= 84 zeroed)
#pragma unroll
        for (int pass = 0; pass < 3; pass++) {
            const int idx4 = tid + pass * 256;       // 0..767 = 96*8 float4s
            const int k  = idx4 >> 3;
            const int f0 = (idx4 & 7) << 2;
            float4 v = make_float4(0.f, 0.f, 0.f, 0.f);
            if (k < NK) v = *(const float4*)(Wg + (size_t)k * WROW + fk + f0);
            *(float4*)&Wl[k][f0] = v;
        }
        // stage mag chunk: 64 frames x 32 f, bf16 -> f32
        {
            const int fr   = tid >> 2;
            const int f0   = (tid & 3) << 3;
            const int ft   = ft0 + fr;
            const int fcol = fk + f0;
            float4 lo = make_float4(0.f, 0.f, 0.f, 0.f);
            float4 hi = make_float4(0.f, 0.f, 0.f, 0.f);
            if (ft < NT && fcol < MROW) {
                const ushort* p = (const ushort*)(mag + (size_t)ft * MROW + fcol);
                ushort4 a = *(const ushort4*)p;
                ushort4 c = *(const ushort4*)(p + 4);
                lo = make_float4(bf2f(a.x), bf2f(a.y), bf2f(a.z), bf2f(a.w));
                hi = make_float4(bf2f(c.x), bf2f(c.y), bf2f(c.z), bf2f(c.w));
            }
            *(float4*)&Ml[fr][f0]     = lo;
            *(float4*)&Ml[fr][f0 + 4] = hi;
        }
        __syncthreads();

#pragma unroll
        for (int f4 = 0; f4 < 8; f4++) {
            float4 wv[6], mv[4];
#pragma unroll
            for (int kk = 0; kk < 6; kk++) wv[kk] = *(const float4*)&Wl[ty * 6 + kk][f4 * 4];
#pragma unroll
            for (int i = 0; i < 4; i++)    mv[i]  = *(const float4*)&Ml[tx + 16 * i][f4 * 4];
#pragma unroll
            for (int kk = 0; kk < 6; kk++)
#pragma unroll
                for (int i = 0; i < 4; i++) {
                    acc[kk][i] += wv[kk].x * mv[i].x + wv[kk].y * mv[i].y
                                + wv[kk].z * mv[i].z + wv[kk].w * mv[i].w;
                }
        }
        __syncthreads();
    }

    // epilogue: log10 + scattered store
#pragma unroll
    for (int kk = 0; kk < 6; kk++) {
        const int k = ty * 6 + kk;
        if (k < NK) {
#pragma unroll
            for (int i = 0; i < 4; i++) {
                const int ft = ft0 + tx + 16 * i;
                if (ft < NT) {
                    const int b = ft / NFRAMES;
                    const int t = ft - b * NFRAMES;
                    out[((size_t)b * NK + k) * NFRAMES + t] = log10f(acc[kk][i] + 1e-10f);
                }
            }
        }
    }
}

extern "C" void kernel_launch(void* const* d_in, const int* in_sizes, int n_in,
                              void* d_out, int out_size, void* d_ws, size_t ws_size,
                              hipStream_t stream) {
    const float* audio = (const float*)d_in[0];
    float* out = (float*)d_out;
    float* ws  = (float*)d_ws;
    __hip_bfloat16* mag = (__hip_bfloat16*)(ws + MAG_FOFF);

    hipLaunchKernelGGL(init_tables_kernel,
                       dim3((NK * WROW + 255) / 256), dim3(256), 0, stream, ws);
    hipLaunchKernelGGL(fft_kernel,
                       dim3(NT), dim3(256), 0, stream, audio, ws, mag);
    hipLaunchKernelGGL(proj_kernel,
                       dim3((NT + TFR - 1) / TFR), dim3(256), 0, stream, ws, mag, out);
}

// Round 3
// 220.143 us; speedup vs baseline: 21.7768x; 2.4548x over previous
//
#include <hip/hip_runtime.h>
#include <hip/hip_bf16.h>
#include <math.h>

#define AUDIO_LEN 1310720
#define NBATCH    16
#define NFRAMES   2561
#define NT        (NBATCH * NFRAMES)   // 40976
#define NFFT      2048
#define HALF_N    1024
#define NK        84
#define NF        1025
#define MROW      1056                 // padded mag row (f16), 1025..1055 zero
#define NCH       33                   // 33*32 = 1056 K-chunks

// ws layout: float offsets for tables, byte offset for mag
#define TW_OFF   0                     // float2[1025]
#define WIN_OFF  2052                  // float[2048]
#define WF_OFF   4104                  // _Float16[33*512*8] pre-fragmented W (byte 16416)
#define MAG_OFF_B 286976               // f16 mag[NT][MROW], 16B aligned

typedef _Float16 h8   __attribute__((ext_vector_type(8)));
typedef float    f32x4 __attribute__((ext_vector_type(4)));

__device__ __forceinline__ void gll16(const void* src, void* dst) {
    __builtin_amdgcn_global_load_lds(
        (const __attribute__((address_space(1))) void*)src,
        (__attribute__((address_space(3))) void*)dst, 16, 0, 0);
}

__global__ __launch_bounds__(256) void init_tables_kernel(float* __restrict__ ws) {
    int i = blockIdx.x * 256 + threadIdx.x;
    // pre-fragmented f16 weights: [ck][slot=mt*64+lane (384..511 zero-pad)][8]
    if (i < NCH * 512 * 8) {
        int i8 = i & 7;
        int c  = i >> 3;
        int ck = c >> 9;
        int cc = c & 511;
        int mt = cc >> 6;
        int l  = cc & 63;
        int k  = mt * 16 + (l & 15);
        int f  = ck * 32 + (l >> 4) * 8 + i8;
        float w = 0.0f;
        if (cc < 384 && k < NK && f < NF) {
            float sf = (float)f * (22050.0f / 2048.0f);
            float cf = 27.5f * exp2f((float)k * (1.0f / 12.0f));
            w = expf(-fabsf(sf - cf) / (0.1f * cf));
        }
        ((_Float16*)(ws + WF_OFF))[i] = (_Float16)w;
    }
    if (i <= HALF_N) {
        double ang = -2.0 * M_PI * (double)i / 2048.0;
        ws[TW_OFF + 2 * i]     = (float)cos(ang);
        ws[TW_OFF + 2 * i + 1] = (float)sin(ang);
    }
    if (i < NFFT) {
        double ang = 2.0 * M_PI * (double)i / 2048.0;
        ws[WIN_OFF + i] = (float)(0.5 * (1.0 - cos(ang)));
    }
}

// ---------------- radix-4 Stockham FFT (5 stages), f16 magnitude out ----------------
__global__ __launch_bounds__(256, 6) void fft_kernel(const float* __restrict__ audio,
                                                     const float* __restrict__ ws,
                                                     _Float16* __restrict__ mag) {
    __shared__ float2 SC[2][HALF_N];
    __shared__ float2 TW[HALF_N + 1];

    const int tid = threadIdx.x;
    const int ft  = blockIdx.x;
    const int b   = ft / NFRAMES;
    const int t   = ft - b * NFRAMES;

    const float2* __restrict__ twg = (const float2*)(ws + TW_OFF);
    const float*  __restrict__ win = ws + WIN_OFF;

    for (int i = tid; i <= HALF_N; i += 256) TW[i] = twg[i];

    const float* __restrict__ ab = audio + (size_t)b * AUDIO_LEN;
    const int base = t * 512 - 1024;
    for (int n = tid; n < NFFT; n += 256) {
        int j = base + n;
        j = (j < 0) ? -j : ((j >= AUDIO_LEN) ? 2 * AUDIO_LEN - 2 - j : j);
        float v = ab[j] * win[n];
        if (n & 1) SC[0][n >> 1].y = v;
        else       SC[0][n >> 1].x = v;
    }
    __syncthreads();

    int cur = 0;
#pragma unroll
    for (int s = 0; s < 5; s++) {
        const int m  = 1 << (2 * s);
        const int q  = tid & (m - 1);
        const int jm = tid & ~(m - 1);       // j*m
        const int o  = q + (jm << 2);        // q + j*4m

        const float2 p0 = SC[cur][tid];
        const float2 p1 = SC[cur][tid + 256];
        const float2 p2 = SC[cur][tid + 512];
        const float2 p3 = SC[cur][tid + 768];

        const float u0x = p0.x + p2.x, u0y = p0.y + p2.y;
        const float u1x = p0.x - p2.x, u1y = p0.y - p2.y;
        const float u2x = p1.x + p3.x, u2y = p1.y + p3.y;
        const float u3x = p1.x - p3.x, u3y = p1.y - p3.y;

        const float2 w1 = TW[jm << 1];       // W_1024^(jm)
        const float2 w2 = TW[jm << 2];       // W_1024^(2jm)
        const float2 w3 = make_float2(w1.x * w2.x - w1.y * w2.y,
                                      w1.x * w2.y + w1.y * w2.x);

        const float t1x = u1x + u3y, t1y = u1y - u3x;   // u1 - i*u3
        const float t3x = u1x - u3y, t3y = u1y + u3x;   // u1 + i*u3
        const float t2x = u0x - u2x, t2y = u0y - u2y;

        SC[cur ^ 1][o]         = make_float2(u0x + u2x, u0y + u2y);
        SC[cur ^ 1][o + m]     = make_float2(w1.x * t1x - w1.y * t1y, w1.x * t1y + w1.y * t1x);
        SC[cur ^ 1][o + 2 * m] = make_float2(w2.x * t2x - w2.y * t2y, w2.x * t2y + w2.y * t2x);
        SC[cur ^ 1][o + 3 * m] = make_float2(w3.x * t3x - w3.y * t3y, w3.x * t3y + w3.y * t3x);
        __syncthreads();
        cur ^= 1;
    }

    // untangle real-input FFT, magnitude, f16 store
    _Float16* __restrict__ mrow = mag + (size_t)ft * MROW;
    for (int k = tid; k <= HALF_N; k += 256) {
        const int k1 = k & (HALF_N - 1);
        const int k2 = (HALF_N - k) & (HALF_N - 1);
        const float2 z = SC[cur][k1];
        const float2 u = SC[cur][k2];
        const float er = 0.5f * (z.x + u.x), ei = 0.5f * (z.y - u.y);
        const float dr = z.x - u.x,          di = z.y + u.y;
        const float pr = 0.5f * di,          pi = -0.5f * dr;
        const float2 w = TW[k];
        const float xr = er + w.x * pr - w.y * pi;
        const float xi = ei + w.x * pi + w.y * pr;
        mrow[k] = (_Float16)sqrtf(xr * xr + xi * xi);
    }
    if (tid < MROW - NF) mrow[NF + tid] = (_Float16)0.0f;
}

// ---------------- MFMA projection: out[96,NT] = Wf * mag^T ----------------
// block: 256 threads (4 waves), 128 frames; wave w -> frames [w*32, w*32+32)
__global__ __launch_bounds__(256) void proj_kernel(const float* __restrict__ ws,
                                                   const _Float16* __restrict__ mag,
                                                   float* __restrict__ out) {
    __shared__ __align__(16) _Float16 As[2][4096];   // [cur][slot=mt*64+lane][8]
    __shared__ __align__(16) _Float16 Bs[2][4096];   // [cur][slot=fr*4+kg][8]

    const int tid  = threadIdx.x;
    const int lane = tid & 63;
    const int w    = tid >> 6;
    const int ft0  = blockIdx.x * 128;

    const _Float16* __restrict__ wf = (const _Float16*)(ws + WF_OFF);

    const int fr = tid >> 2, kg = tid & 3;
    int ftc0 = ft0 + fr;       if (ftc0 >= NT) ftc0 = NT - 1;
    int ftc1 = ft0 + fr + 64;  if (ftc1 >= NT) ftc1 = NT - 1;
    const _Float16* bsrc0 = mag + (size_t)ftc0 * MROW + kg * 8;
    const _Float16* bsrc1 = mag + (size_t)ftc1 * MROW + kg * 8;

#define STAGE(nb, ck)  do {                                                   \
        const _Float16* asrc = wf + (size_t)(ck) * 4096;                      \
        gll16(asrc + (size_t)tid * 8,         &As[nb][tid * 8]);              \
        gll16(asrc + (size_t)(tid + 256) * 8, &As[nb][(tid + 256) * 8]);      \
        gll16(bsrc0 + (ck) * 32,              &Bs[nb][tid * 8]);              \
        gll16(bsrc1 + (ck) * 32,              &Bs[nb][(tid + 256) * 8]);      \
    } while (0)

    f32x4 acc[6][2];
#pragma unroll
    for (int mt = 0; mt < 6; mt++)
#pragma unroll
        for (int nt = 0; nt < 2; nt++) acc[mt][nt] = (f32x4)0.0f;

    STAGE(0, 0);
    int cur = 0;
    for (int ck = 0; ck < NCH; ck++) {
        if (ck + 1 < NCH) {
            STAGE(cur ^ 1, ck + 1);
            asm volatile("s_waitcnt vmcnt(4)" ::: "memory");
        } else {
            asm volatile("s_waitcnt vmcnt(0)" ::: "memory");
        }
        __builtin_amdgcn_s_barrier();

        h8 a[6], bb[2];
#pragma unroll
        for (int mt = 0; mt < 6; mt++)
            a[mt] = *(const h8*)&As[cur][(mt * 64 + lane) * 8];
#pragma unroll
        for (int nt = 0; nt < 2; nt++) {
            const int slot = (w * 32 + nt * 16 + (lane & 15)) * 4 + (lane >> 4);
            bb[nt] = *(const h8*)&Bs[cur][slot * 8];
        }
#pragma unroll
        for (int mt = 0; mt < 6; mt++)
#pragma unroll
            for (int nt = 0; nt < 2; nt++)
                acc[mt][nt] = __builtin_amdgcn_mfma_f32_16x16x32_f16(a[mt], bb[nt], acc[mt][nt], 0, 0, 0);

        asm volatile("" ::: "memory");
        __builtin_amdgcn_s_barrier();
        cur ^= 1;
    }
#undef STAGE

    // epilogue: D row = bin = mt*16 + (lane>>4)*4 + r ; D col = frame = ft0+w*32+nt*16+(lane&15)
    const int fcol = lane & 15, frow = lane >> 4;
#pragma unroll
    for (int nt = 0; nt < 2; nt++) {
        const int ft = ft0 + w * 32 + nt * 16 + fcol;
        if (ft < NT) {
            const int b = ft / NFRAMES;
            const int t = ft - b * NFRAMES;
#pragma unroll
            for (int mt = 0; mt < 6; mt++)
#pragma unroll
                for (int r = 0; r < 4; r++) {
                    const int k = mt * 16 + frow * 4 + r;
                    if (k < NK)
                        out[((size_t)b * NK + k) * NFRAMES + t] = log10f(acc[mt][nt][r] + 1e-10f);
                }
        }
    }
}

extern "C" void kernel_launch(void* const* d_in, const int* in_sizes, int n_in,
                              void* d_out, int out_size, void* d_ws, size_t ws_size,
                              hipStream_t stream) {
    const float* audio = (const float*)d_in[0];
    float* out = (float*)d_out;
    float* ws  = (float*)d_ws;
    _Float16* mag = (_Float16*)((char*)d_ws + MAG_OFF_B);

    hipLaunchKernelGGL(init_tables_kernel, dim3(528), dim3(256), 0, stream, ws);
    hipLaunchKernelGGL(fft_kernel, dim3(NT), dim3(256), 0, stream, audio, ws, mag);
    hipLaunchKernelGGL(proj_kernel, dim3((NT + 127) / 128), dim3(256), 0, stream, ws, mag, out);
}

// Round 4
// 146.649 us; speedup vs baseline: 32.6904x; 1.5012x over previous
//
#include <hip/hip_runtime.h>
#include <hip/hip_bf16.h>
#include <math.h>

#define AUDIO_LEN 1310720
#define NBATCH    16
#define NFRAMES   2561
#define NT        (NBATCH * NFRAMES)   // 40976
#define NFFT      2048
#define HALF_N    1024
#define NK        84
#define NF        1025
#define MROW      1056                 // padded mag row (f16), 1025..1055 zero
#define NCH       33                   // 33*32 = 1056 K-chunks

// ws layout: float offsets for tables, byte offset for mag
#define TW_OFF   0                     // float2[1025]
#define WIN_OFF  2052                  // float[2048]
#define WF_OFF   4104                  // _Float16[33*512*8] pre-fragmented W (byte 16416)
#define MAG_OFF_B 286976               // f16 mag[NT][MROW], 16B aligned

typedef _Float16 h8    __attribute__((ext_vector_type(8)));
typedef float    f32x4 __attribute__((ext_vector_type(4)));

__device__ __forceinline__ void gll16(const void* src, void* dst) {
    __builtin_amdgcn_global_load_lds(
        (const __attribute__((address_space(1))) void*)src,
        (__attribute__((address_space(3))) void*)dst, 16, 0, 0);
}

__device__ __forceinline__ float2 cmul(float2 a, float2 b) {
    return make_float2(a.x * b.x - a.y * b.y, a.x * b.y + a.y * b.x);
}

#define DFT4(p0, p1, p2, p3, y0, y1, y2, y3) do {                        \
    const float u0x = (p0).x + (p2).x, u0y = (p0).y + (p2).y;            \
    const float u1x = (p0).x - (p2).x, u1y = (p0).y - (p2).y;            \
    const float u2x = (p1).x + (p3).x, u2y = (p1).y + (p3).y;            \
    const float u3x = (p1).x - (p3).x, u3y = (p1).y - (p3).y;            \
    (y0) = make_float2(u0x + u2x, u0y + u2y);                            \
    (y1) = make_float2(u1x + u3y, u1y - u3x);                            \
    (y2) = make_float2(u0x - u2x, u0y - u2y);                            \
    (y3) = make_float2(u1x - u3y, u1y + u3x);                            \
} while (0)

// DFT-16 in registers: two radix-4 levels + constant omega16 twiddles
__device__ __forceinline__ void dft16(float2* v) {
    const float C = 0.92387953251128674f;   // cos(pi/8)
    const float S = 0.38268343236508978f;   // sin(pi/8)
    const float H = 0.70710678118654752f;
    float2 A[16];  // A[b*4 + d1]
#pragma unroll
    for (int b = 0; b < 4; b++)
        DFT4(v[b], v[b + 4], v[b + 8], v[b + 12],
             A[b * 4 + 0], A[b * 4 + 1], A[b * 4 + 2], A[b * 4 + 3]);
    // B_b[d1] = w16^{d1*b} * A_b[d1]
    A[4 + 1]  = cmul(A[4 + 1],  make_float2(C, -S));   // w^1
    A[4 + 2]  = cmul(A[4 + 2],  make_float2(H, -H));   // w^2
    A[4 + 3]  = cmul(A[4 + 3],  make_float2(S, -C));   // w^3
    A[8 + 1]  = cmul(A[8 + 1],  make_float2(H, -H));   // w^2
    A[8 + 2]  = make_float2(A[8 + 2].y, -A[8 + 2].x);  // w^4 = -i
    A[8 + 3]  = cmul(A[8 + 3],  make_float2(-H, -H));  // w^6
    A[12 + 1] = cmul(A[12 + 1], make_float2(S, -C));   // w^3
    A[12 + 2] = cmul(A[12 + 2], make_float2(-H, -H));  // w^6
    A[12 + 3] = cmul(A[12 + 3], make_float2(-C, S));   // w^9
#pragma unroll
    for (int d1 = 0; d1 < 4; d1++)
        DFT4(A[0 + d1], A[4 + d1], A[8 + d1], A[12 + d1],
             v[d1], v[d1 + 4], v[d1 + 8], v[d1 + 12]);
}

// v[i] *= w1^i, i=1..15 (power tree from one loaded twiddle)
__device__ __forceinline__ void twiddle15(float2* v, float2 w1) {
    float2 wp[16];
    wp[1]  = w1;
    wp[2]  = cmul(w1, w1);
    wp[3]  = cmul(wp[2], w1);
    wp[4]  = cmul(wp[2], wp[2]);
    wp[5]  = cmul(wp[4], w1);
    wp[6]  = cmul(wp[3], wp[3]);
    wp[7]  = cmul(wp[4], wp[3]);
    wp[8]  = cmul(wp[4], wp[4]);
    wp[9]  = cmul(wp[8], w1);
    wp[10] = cmul(wp[5], wp[5]);
    wp[11] = cmul(wp[8], wp[3]);
    wp[12] = cmul(wp[6], wp[6]);
    wp[13] = cmul(wp[8], wp[5]);
    wp[14] = cmul(wp[7], wp[7]);
    wp[15] = cmul(wp[8], wp[7]);
#pragma unroll
    for (int i = 1; i < 16; i++) v[i] = cmul(v[i], wp[i]);
}

__global__ __launch_bounds__(256) void init_tables_kernel(float* __restrict__ ws) {
    int i = blockIdx.x * 256 + threadIdx.x;
    // pre-fragmented f16 weights: [ck][slot=mt*64+lane (384..511 zero-pad)][8]
    if (i < NCH * 512 * 8) {
        int i8 = i & 7;
        int c  = i >> 3;
        int ck = c >> 9;
        int cc = c & 511;
        int mt = cc >> 6;
        int l  = cc & 63;
        int k  = mt * 16 + (l & 15);
        int f  = ck * 32 + (l >> 4) * 8 + i8;
        float w = 0.0f;
        if (cc < 384 && k < NK && f < NF) {
            float sf = (float)f * (22050.0f / 2048.0f);
            float cf = 27.5f * exp2f((float)k * (1.0f / 12.0f));
            w = expf(-fabsf(sf - cf) / (0.1f * cf));
        }
        ((_Float16*)(ws + WF_OFF))[i] = (_Float16)w;
    }
    if (i <= HALF_N) {
        double ang = -2.0 * M_PI * (double)i / 2048.0;
        ws[TW_OFF + 2 * i]     = (float)cos(ang);
        ws[TW_OFF + 2 * i + 1] = (float)sin(ang);
    }
    if (i < NFFT) {
        double ang = 2.0 * M_PI * (double)i / 2048.0;
        ws[WIN_OFF + i] = (float)(0.5 * (1.0 - cos(ang)));
    }
}

// ---- 1 wave = 1 frame; 1024-pt FFT as 16x16x4, 2 LDS round-trips, 0 barriers ----
__global__ __launch_bounds__(64) void fft_kernel(const float* __restrict__ audio,
                                                 const float* __restrict__ ws,
                                                 _Float16* __restrict__ mag) {
    __shared__ float2 A[HALF_N];   // 8 KB, private to this single-wave block

    const int t  = threadIdx.x;    // lane 0..63
    const int ft = blockIdx.x;
    const int b  = ft / NFRAMES;
    const int tf = ft - b * NFRAMES;

    const float2* __restrict__ TW = (const float2*)(ws + TW_OFF);
    const float2* __restrict__ W2 = (const float2*)(ws + WIN_OFF);
    const float*  __restrict__ ab = audio + (size_t)b * AUDIO_LEN;
    const int base = tf * 512 - 1024;

    // load + window + even/odd complex pack: x[l] = z[t + 64l]
    float2 x[16];
    if (tf >= 2 && tf <= 2558) {
        const float2* __restrict__ a2 = (const float2*)(ab + base);
#pragma unroll
        for (int l = 0; l < 16; l++) {
            const int p = t + 64 * l;
            const float2 v  = a2[p];
            const float2 wv = W2[p];
            x[l] = make_float2(v.x * wv.x, v.y * wv.y);
        }
    } else {
#pragma unroll
        for (int l = 0; l < 16; l++) {
            const int p = t + 64 * l;
            int j0 = base + 2 * p, j1 = j0 + 1;
            j0 = (j0 < 0) ? -j0 : ((j0 >= AUDIO_LEN) ? 2 * AUDIO_LEN - 2 - j0 : j0);
            j1 = (j1 < 0) ? -j1 : ((j1 >= AUDIO_LEN) ? 2 * AUDIO_LEN - 2 - j1 : j1);
            const float2 wv = W2[p];
            x[l] = make_float2(ab[j0] * wv.x, ab[j1] * wv.y);
        }
    }

    // ---- stage 0: radix-16, m=1, jm=t; out[16t + d] ----
    dft16(x);
    twiddle15(x, TW[2 * t]);                 // W_1024^t
    {
        float4* A4 = (float4*)A;
        const int m = (t ^ (t >> 3)) & 7;    // XOR swizzle (pair-slot granularity)
#pragma unroll
        for (int dp = 0; dp < 8; dp++)
            A4[8 * t + (dp ^ m)] = make_float4(x[2 * dp].x,     x[2 * dp].y,
                                               x[2 * dp + 1].x, x[2 * dp + 1].y);
    }

    // swizzled f2 addresses for the stride-64 read pattern (reused by stage 2)
    int adr[16];
#pragma unroll
    for (int s = 0; s < 16; s++) {
        const int p = t + 64 * s;
        adr[s] = p ^ (((((p >> 4) ^ (p >> 7)) & 7)) << 1);
    }

    // ---- stage 1: radix-16, m=16; in[t+64l] -> out[q + 256j + 16d] ----
#pragma unroll
    for (int l = 0; l < 16; l++) x[l] = A[adr[l]];
    dft16(x);
    twiddle15(x, TW[32 * (t >> 4)]);         // W_64^(t>>4)
    {
        const int basei = (t & 15) + 256 * (t >> 4);
#pragma unroll
        for (int d = 0; d < 16; d++) {
            const int p = basei + 16 * d;
            A[p ^ (((((p >> 4) ^ (p >> 7)) & 7)) << 1)] = x[d];
        }
    }

    // ---- stage 2: radix-4, m=256, no twiddles; thread ends holding X[t + 64s] ----
#pragma unroll
    for (int s = 0; s < 16; s++) x[s] = A[adr[s]];
    float2 xf[16];
#pragma unroll
    for (int w = 0; w < 4; w++)
        DFT4(x[w], x[w + 4], x[w + 8], x[w + 12],
             xf[w], xf[w + 4], xf[w + 8], xf[w + 12]);

    // ---- rfft untangle via lane exchange + magnitude ----
    const float CS[16] = { 1.0f,               0.98078528040323f,  0.92387953251129f,  0.83146961230255f,
                           0.70710678118655f,  0.55557023301960f,  0.38268343236509f,  0.19509032201613f,
                           0.0f,              -0.19509032201613f, -0.38268343236509f, -0.55557023301960f,
                          -0.70710678118655f, -0.83146961230255f, -0.92387953251129f, -0.98078528040323f };
    const float SN[16] = { 0.0f,               0.19509032201613f,  0.38268343236509f,  0.55557023301960f,
                           0.70710678118655f,  0.83146961230255f,  0.92387953251129f,  0.98078528040323f,
                           1.0f,               0.98078528040323f,  0.92387953251129f,  0.83146961230255f,
                           0.70710678118655f,  0.55557023301960f,  0.38268343236509f,  0.19509032201613f };

    const int   src = (64 - t) & 63;
    const float2 wt = TW[t];
    _Float16* __restrict__ mrow = mag + (size_t)ft * MROW;
#pragma unroll
    for (int s = 0; s < 16; s++) {
        float ux = __shfl(xf[15 - s].x, src, 64);
        float uy = __shfl(xf[15 - s].y, src, 64);
        if (t == 0) { ux = xf[(16 - s) & 15].x; uy = xf[(16 - s) & 15].y; }
        const float2 z = xf[s];
        const float er = 0.5f * (z.x + ux), ei = 0.5f * (z.y - uy);
        const float dr = z.x - ux,          di = z.y + uy;
        const float pr = 0.5f * di,         pi = -0.5f * dr;
        const float wkx = wt.x * CS[s] + wt.y * SN[s];     // wt * e^{-i pi s/16}
        const float wky = -wt.x * SN[s] + wt.y * CS[s];
        const float xr = er + wkx * pr - wky * pi;
        const float xi = ei + wkx * pi + wky * pr;
        mrow[t + 64 * s] = (_Float16)sqrtf(xr * xr + xi * xi);
    }
    if (t == 0) mrow[1024] = (_Float16)fabsf(xf[0].x - xf[0].y);   // Nyquist
    if (t < MROW - NF) mrow[NF + t] = (_Float16)0.0f;              // zero pad
}

// ---------------- MFMA projection: out[96,NT] = Wf * mag^T ----------------
__global__ __launch_bounds__(256) void proj_kernel(const float* __restrict__ ws,
                                                   const _Float16* __restrict__ mag,
                                                   float* __restrict__ out) {
    __shared__ __align__(16) _Float16 As[2][4096];   // [cur][slot=mt*64+lane][8]
    __shared__ __align__(16) _Float16 Bs[2][4096];   // [cur][slot=fr*4+kg][8]

    const int tid  = threadIdx.x;
    const int lane = tid & 63;
    const int w    = tid >> 6;
    const int ft0  = blockIdx.x * 128;

    const _Float16* __restrict__ wf = (const _Float16*)(ws + WF_OFF);

    const int fr = tid >> 2, kg = tid & 3;
    int ftc0 = ft0 + fr;       if (ftc0 >= NT) ftc0 = NT - 1;
    int ftc1 = ft0 + fr + 64;  if (ftc1 >= NT) ftc1 = NT - 1;
    const _Float16* bsrc0 = mag + (size_t)ftc0 * MROW + kg * 8;
    const _Float16* bsrc1 = mag + (size_t)ftc1 * MROW + kg * 8;

#define STAGE(nb, ck)  do {                                                   \
        const _Float16* asrc = wf + (size_t)(ck) * 4096;                      \
        gll16(asrc + (size_t)tid * 8,         &As[nb][tid * 8]);              \
        gll16(asrc + (size_t)(tid + 256) * 8, &As[nb][(tid + 256) * 8]);      \
        gll16(bsrc0 + (ck) * 32,              &Bs[nb][tid * 8]);              \
        gll16(bsrc1 + (ck) * 32,              &Bs[nb][(tid + 256) * 8]);      \
    } while (0)

    f32x4 acc[6][2];
#pragma unroll
    for (int mt = 0; mt < 6; mt++)
#pragma unroll
        for (int nt = 0; nt < 2; nt++) acc[mt][nt] = (f32x4)0.0f;

    STAGE(0, 0);
    int cur = 0;
    for (int ck = 0; ck < NCH; ck++) {
        if (ck + 1 < NCH) {
            STAGE(cur ^ 1, ck + 1);
            asm volatile("s_waitcnt vmcnt(4)" ::: "memory");
        } else {
            asm volatile("s_waitcnt vmcnt(0)" ::: "memory");
        }
        __builtin_amdgcn_s_barrier();

        h8 a[6], bb[2];
#pragma unroll
        for (int mt = 0; mt < 6; mt++)
            a[mt] = *(const h8*)&As[cur][(mt * 64 + lane) * 8];
#pragma unroll
        for (int nt = 0; nt < 2; nt++) {
            const int slot = (w * 32 + nt * 16 + (lane & 15)) * 4 + (lane >> 4);
            bb[nt] = *(const h8*)&Bs[cur][slot * 8];
        }
#pragma unroll
        for (int mt = 0; mt < 6; mt++)
#pragma unroll
            for (int nt = 0; nt < 2; nt++)
                acc[mt][nt] = __builtin_amdgcn_mfma_f32_16x16x32_f16(a[mt], bb[nt], acc[mt][nt], 0, 0, 0);

        asm volatile("" ::: "memory");
        __builtin_amdgcn_s_barrier();
        cur ^= 1;
    }
#undef STAGE

    const int fcol = lane & 15, frow = lane >> 4;
#pragma unroll
    for (int nt = 0; nt < 2; nt++) {
        const int ft = ft0 + w * 32 + nt * 16 + fcol;
        if (ft < NT) {
            const int b = ft / NFRAMES;
            const int t = ft - b * NFRAMES;
#pragma unroll
            for (int mt = 0; mt < 6; mt++)
#pragma unroll
                for (int r = 0; r < 4; r++) {
                    const int k = mt * 16 + frow * 4 + r;
                    if (k < NK)
                        out[((size_t)b * NK + k) * NFRAMES + t] = log10f(acc[mt][nt][r] + 1e-10f);
                }
        }
    }
}

extern "C" void kernel_launch(void* const* d_in, const int* in_sizes, int n_in,
                              void* d_out, int out_size, void* d_ws, size_t ws_size,
                              hipStream_t stream) {
    const float* audio = (const float*)d_in[0];
    float* out = (float*)d_out;
    float* ws  = (float*)d_ws;
    _Float16* mag = (_Float16*)((char*)d_ws + MAG_OFF_B);

    hipLaunchKernelGGL(init_tables_kernel, dim3(528), dim3(256), 0, stream, ws);
    hipLaunchKernelGGL(fft_kernel, dim3(NT), dim3(64), 0, stream, audio, ws, mag);
    hipLaunchKernelGGL(proj_kernel, dim3((NT + 127) / 128), dim3(256), 0, stream, ws, mag, out);
}